// Round 4
// baseline (103.213 us; speedup 1.0000x reference)
//
#include <hip/hip_runtime.h>

typedef unsigned long long u64;

constexpr int D = 48, H = 384, W = 384;
constexpr int WPR = 6;                    // 384 bits / 64 per row
constexpr int NVOX = D * H * W;           // 7,077,888
constexpr int NWVOL = D * H * WPR;        // 110,592 packed words per volume
constexpr int NWZ = H * WPR;              // words per z-slice (largest mode) = 2304
constexpr size_t THIN_SMEM = (size_t)6 * NWZ * 8;   // A,B,C0,C1,U0,U1 = 110,592 B

// full adder: s = a+b+c (bit-sliced), cy = carry
__device__ __forceinline__ void fa(u64 a, u64 b, u64 c, u64& s, u64& cy) {
  u64 x = a ^ b;
  s = x ^ c;
  cy = (a & b) | (c & x);
}

// One Zhang-Suen subiteration for one packed word, neighbors in registers.
// bit j = column base+j; east -> (w>>1)|(next<<63), west -> (w<<1)|(prev>>63)
__device__ __forceinline__ u64 zs_regs(u64 w00, u64 w01, u64 w02,
                                       u64 w10, u64 w11, u64 w12,
                                       u64 w20, u64 w21, u64 w22, bool first) {
  const u64 P2 = w01;                          // N
  const u64 P3 = (w01 >> 1) | (w02 << 63);     // NE
  const u64 P4 = (w11 >> 1) | (w12 << 63);     // E
  const u64 P5 = (w21 >> 1) | (w22 << 63);     // SE
  const u64 P6 = w21;                          // S
  const u64 P7 = (w21 << 1) | (w20 >> 63);     // SW
  const u64 P8 = (w11 << 1) | (w10 >> 63);     // W
  const u64 P9 = (w01 << 1) | (w00 >> 63);     // NW

  u64 s1, c1, s2, c2, s3, c3, u0, u1, v1, v2;
  fa(P2, P3, P4, s1, c1);
  fa(P5, P6, P7, s2, c2);
  fa(P8, P9, 0ull, s3, c3);
  fa(s1, s2, s3, u0, u1);
  fa(c1, c2, c3, v1, v2);
  u64 b1 = u1 ^ v1, k2 = u1 & v1;
  u64 b2 = v2 ^ k2, b3 = v2 & k2;
  u64 condB = (b1 | b2 | b3) & ~(b3 | (b2 & b1 & u0));   // 2<=B<=6

  u64 t0 = ~P2 & P3, t1 = ~P3 & P4, t2 = ~P4 & P5, t3 = ~P5 & P6;
  u64 t4 = ~P6 & P7, t5 = ~P7 & P8, t6 = ~P8 & P9, t7 = ~P9 & P2;
  fa(t0, t1, t2, s1, c1);
  fa(t3, t4, t5, s2, c2);
  fa(t6, t7, 0ull, s3, c3);
  fa(s1, s2, s3, u0, u1);
  fa(c1, c2, c3, v1, v2);
  u64 a1 = u1 ^ v1, j2 = u1 & v1;
  u64 a2 = v2 ^ j2, a3 = v2 & j2;
  u64 condA = u0 & ~(a1 | a2 | a3);                      // A == 1

  u64 cc = first ? ((~(P2 & P4 & P6)) & (~(P4 & P6 & P8)))
                 : ((~(P2 & P4 & P8)) & (~(P2 & P6 & P8)));
  return w11 & ~(condB & condA & cc);
}

// One pruned subiteration pass. Segments of 3 contiguous words per thread.
// CR/UR: change mask of previous pass / union of previous two passes (read).
// CW/UW: this pass's change mask / union written (only for dirty segments).
// Clean segment => output == dst's current content (2 passes old) => skip all writes.
template<int R, bool FIRST>
__device__ __forceinline__ void subpass(const u64* __restrict__ src, u64* __restrict__ dst,
                                        u64* __restrict__ CW, const u64* __restrict__ CR,
                                        u64* __restrict__ UW, const u64* __restrict__ UR,
                                        int* chgflag, int tid, int nthr) {
  constexpr int NSEG = R * 2;                 // (R*WPR)/3
  int anych = 0;
  for (int s = tid; s < NSEG; s += nthr) {
    const int r = s >> 1;
    const int c0 = (s & 1) * 3;
    const int idx0 = r * WPR + c0;
    const bool hL = (c0 > 0);                 // has word to the left (c0==3)
    const bool hR = !hL;                      // has word to the right (c0==0)

    // ---- pixel-accurate dirty test: exact 3-row x (3 words + edge bits) halo ----
    u64 d;
    {
      const u64* u = UR + idx0;
      d = u[0] | u[1] | u[2];
      if (hL) d |= u[-1] >> 63;
      if (hR) d |= u[3] << 63;
      if (r > 0) {
        const u64* um = u - WPR;
        d |= um[0] | um[1] | um[2];
        if (hL) d |= um[-1] >> 63;
        if (hR) d |= um[3] << 63;
      }
      if (r < R - 1) {
        const u64* up = u + WPR;
        d |= up[0] | up[1] | up[2];
        if (hL) d |= up[-1] >> 63;
        if (hR) d |= up[3] << 63;
      }
    }
    if (!d) continue;                         // clean: no compute, no writes

    // ---- load 3x5 neighbor block into registers (zero-padded borders) ----
    u64 a0 = 0, a1 = 0, a2 = 0, a3 = 0, a4 = 0;
    u64 b0 = 0, b1, b2, b3, b4 = 0;
    u64 g0 = 0, g1 = 0, g2 = 0, g3 = 0, g4 = 0;
    const u64* rb = src + idx0;
    b1 = rb[0]; b2 = rb[1]; b3 = rb[2];
    if (hL) b0 = rb[-1];
    if (hR) b4 = rb[3];
    if (r > 0) {
      const u64* ra = rb - WPR;
      a1 = ra[0]; a2 = ra[1]; a3 = ra[2];
      if (hL) a0 = ra[-1];
      if (hR) a4 = ra[3];
    }
    if (r < R - 1) {
      const u64* rg = rb + WPR;
      g1 = rg[0]; g2 = rg[1]; g3 = rg[2];
      if (hL) g0 = rg[-1];
      if (hR) g4 = rg[3];
    }

    const u64 n0 = b1 ? zs_regs(a0, a1, a2, b0, b1, b2, g0, g1, g2, FIRST) : 0;
    const u64 n1 = b2 ? zs_regs(a1, a2, a3, b1, b2, b3, g1, g2, g3, FIRST) : 0;
    const u64 n2 = b3 ? zs_regs(a2, a3, a4, b2, b3, b4, g2, g3, g4, FIRST) : 0;
    const u64 c0m = n0 ^ b1, c1m = n1 ^ b2, c2m = n2 ^ b3;
    dst[idx0] = n0; dst[idx0 + 1] = n1; dst[idx0 + 2] = n2;
    CW[idx0] = c0m; CW[idx0 + 1] = c1m; CW[idx0 + 2] = c2m;
    UW[idx0]     = c0m | CR[idx0];
    UW[idx0 + 1] = c1m | CR[idx0 + 1];
    UW[idx0 + 2] = c2m | CR[idx0 + 2];
    anych |= ((c0m | c1m | c2m) != 0ull);
  }
  if (anych) *chgflag = 1;
}

// MODE 0: slice=z, rows r=y, cols=x  -> atomicOr into skelZY (packed x)
// MODE 1: slice=y, rows r=z, cols=x  -> atomicOr into skelZY (packed x)
// MODE 2: slice=x, rows r=z, cols=y  -> store to skelX (packed y, layout [z][x][yw])
template<int R, int MODE>
__device__ __forceinline__ void thin_body(const u64* __restrict__ maskP,
                                          u64* __restrict__ skelZY,
                                          u64* __restrict__ skelX,
                                          int slice,
                                          u64* Abuf, u64* Bbuf,
                                          u64* C0, u64* C1, u64* U0, u64* U1,
                                          int* s_chg) {
  constexpr int NW = R * WPR;
  const int tid = threadIdx.x;
  const int nthr = blockDim.x;

  // ---- load packed slice into LDS ----
  if (MODE == 0) {
    for (int idx = tid; idx < NW; idx += nthr) {
      int r = idx / WPR, wc = idx - r * WPR;
      Abuf[idx] = maskP[(slice * H + r) * WPR + wc];
    }
  } else if (MODE == 1) {
    for (int idx = tid; idx < NW; idx += nthr) {
      int r = idx / WPR, wc = idx - r * WPR;
      Abuf[idx] = maskP[(r * H + slice) * WPR + wc];
    }
  } else {
    const int lane = tid & 63, wave = tid >> 6, nwv = nthr >> 6;
    const int xw = slice >> 6, xb = slice & 63;
    for (int idx = wave; idx < NW; idx += nwv) {
      int r = idx / WPR, wc = idx - r * WPR;
      int c = wc * 64 + lane;                     // c = y
      u64 bit = (maskP[(r * H + c) * WPR + xw] >> xb) & 1ull;
      u64 w = __ballot(bit != 0);
      if (lane == 0) Abuf[idx] = w;
    }
  }

  // init: force first two passes all-dirty (pass1 reads U1; pass2 reads U0=ch1|C1=ones)
  for (int i = tid; i < NW; i += nthr) { C1[i] = ~0ull; U1[i] = ~0ull; }
  if (tid < 2) s_chg[tid] = 0;
  __syncthreads();

  // ---- iterate Zhang-Suen to convergence, pixel-pruned ----
  int p = 0;
  while (true) {
    if (tid == 0) s_chg[p ^ 1] = 0;   // next iteration's flag; other slot untouched
    subpass<R, true >(Abuf, Bbuf, C0, C1, U0, U1, &s_chg[p], tid, nthr);
    __syncthreads();
    subpass<R, false>(Bbuf, Abuf, C1, C0, U1, U0, &s_chg[p], tid, nthr);
    __syncthreads();
    const int stop = (s_chg[p] == 0);
    p ^= 1;
    __syncthreads();                  // protects s_chg read vs next iter's clear
    if (stop) break;
  }

  // ---- writeback ----
  for (int idx = tid; idx < NW; idx += nthr) {
    u64 w = Abuf[idx];
    if (!w) continue;                              // targets are zero-initialized
    int r = idx / WPR, wc = idx - r * WPR;
    if (MODE == 0)      atomicOr(&skelZY[(slice * H + r) * WPR + wc], w);
    else if (MODE == 1) atomicOr(&skelZY[(r * H + slice) * WPR + wc], w);
    else                skelX[(r * W + slice) * WPR + wc] = w;
  }
}

__global__ __launch_bounds__(768) void thin_all(const u64* __restrict__ maskP,
                                                u64* __restrict__ skelZY,
                                                u64* __restrict__ skelX) {
  extern __shared__ u64 smem[];
  __shared__ int s_chg[2];
  u64* Abuf = smem;
  u64* Bbuf = Abuf + NWZ;
  u64* C0 = Bbuf + NWZ;
  u64* C1 = C0 + NWZ;
  u64* U0 = C1 + NWZ;
  u64* U1 = U0 + NWZ;
  const int b = blockIdx.x;
  if (b < D) {
    thin_body<H, 0>(maskP, skelZY, skelX, b, Abuf, Bbuf, C0, C1, U0, U1, s_chg);
  } else if (b < D + H) {
    thin_body<D, 1>(maskP, skelZY, skelX, b - D, Abuf, Bbuf, C0, C1, U0, U1, s_chg);
  } else {
    thin_body<D, 2>(maskP, skelZY, skelX, b - D - H, Abuf, Bbuf, C0, C1, U0, U1, s_chg);
  }
}

// Pack mask bits (v==1.0f) along x; zero the two skeleton accumulators.
__global__ void init_pack(const float* __restrict__ in, u64* __restrict__ maskP,
                          u64* __restrict__ skelZY, u64* __restrict__ skelX) {
  const int lane = threadIdx.x & 63;
  const int gwave = (blockIdx.x * blockDim.x + threadIdx.x) >> 6;
  const int nwaves = (gridDim.x * blockDim.x) >> 6;
  for (int widx = gwave; widx < NWVOL; widx += nwaves) {
    float v = in[(size_t)widx * 64 + lane];
    u64 w = __ballot(v == 1.0f);
    if (lane == 0) {
      maskP[widx] = w;
      skelZY[widx] = 0;
      skelX[widx] = 0;
    }
  }
}

// Transpose skelX ([z][x][yw], packed y) into packed-x layout, OR into skelZY.
// One wave per 64x64 bit tile: z fixed, x = xw*64+lane, y = yw*64+j.
__global__ void transpose_or(const u64* __restrict__ skelX,
                             u64* __restrict__ skelZY) {
  const int gw = (blockIdx.x * blockDim.x + threadIdx.x) >> 6;   // tile id
  const int lane = threadIdx.x & 63;
  const int z = gw / 36, rem = gw - z * 36;
  const int yw = rem / 6, xw = rem - yw * 6;
  const int x = xw * 64 + lane;
  const u64 wx = skelX[(z * W + x) * WPR + yw];   // bits indexed by y
  u64 mine = 0;
  #pragma unroll 8
  for (int j = 0; j < 64; ++j) {
    u64 wj = __ballot((wx >> j) & 1ull);          // bit l = pixel(y=yw*64+j, x=xw*64+l)
    if (lane == j) mine = wj;
  }
  const int y = yw * 64 + lane;
  if (mine) skelZY[(z * H + y) * WPR + xw] |= mine;   // exclusive owner per word
}

// Word-parallel 6-connected dilation + mask + expand to float4.
__global__ void dilate_expand(const u64* __restrict__ maskP,
                              const u64* __restrict__ skelZY,
                              float* __restrict__ out) {
  const int idx = blockIdx.x * blockDim.x + threadIdx.x;   // one float4 per thread
  if (idx >= NVOX / 4) return;
  const int i4 = idx * 4;
  const int wi = i4 >> 6;
  const int wc = wi % WPR;
  const int row = wi / WPR;        // row = z*H + y
  const int y = row % H;
  const int z = row / H;

  const u64 S = skelZY[wi];
  const u64 L = (wc > 0) ? skelZY[wi - 1] : 0ull;
  const u64 Rw = (wc < WPR - 1) ? skelZY[wi + 1] : 0ull;
  u64 d = S | (S << 1) | (L >> 63) | (S >> 1) | (Rw << 63);
  if (y > 0)     d |= skelZY[wi - WPR];
  if (y < H - 1) d |= skelZY[wi + WPR];
  if (z > 0)     d |= skelZY[wi - H * WPR];
  if (z < D - 1) d |= skelZY[wi + H * WPR];
  const u64 r = d & maskP[wi];

  const int sh = i4 & 63;
  float4 o;
  o.x = (float)((r >> (sh + 0)) & 1ull);
  o.y = (float)((r >> (sh + 1)) & 1ull);
  o.z = (float)((r >> (sh + 2)) & 1ull);
  o.w = (float)((r >> (sh + 3)) & 1ull);
  *reinterpret_cast<float4*>(out + i4) = o;
}

extern "C" void kernel_launch(void* const* d_in, const int* in_sizes, int n_in,
                              void* d_out, int out_size, void* d_ws, size_t ws_size,
                              hipStream_t stream) {
  const float* in = (const float*)d_in[0];
  float* out = (float*)d_out;
  u64* wsw = (u64*)d_ws;                 // need 3 * 110592 * 8 B = 2.65 MB
  u64* maskP = wsw;
  u64* skelZY = wsw + NWVOL;
  u64* skelX = wsw + 2 * NWVOL;

  (void)hipFuncSetAttribute((const void*)thin_all,
                            hipFuncAttributeMaxDynamicSharedMemorySize,
                            (int)THIN_SMEM);

  init_pack<<<864, 256, 0, stream>>>(in, maskP, skelZY, skelX);
  thin_all<<<D + H + W, 768, THIN_SMEM, stream>>>(maskP, skelZY, skelX);
  transpose_or<<<(NWVOL + 255) / 256, 256, 0, stream>>>(skelX, skelZY);
  dilate_expand<<<(NVOX / 4 + 255) / 256, 256, 0, stream>>>(maskP, skelZY, out);
}